// Round 1
// baseline (197.615 us; speedup 1.0000x reference)
//
#include <hip/hip_runtime.h>

// DCT_18769007084406: RGB->YCbCr (1x1 conv) -> 8x8 stride-8 block DCT
// (grouped conv) -> 32x repeated (t-min)/d normalization (closed form).
//
// x:      [32, 3, 512, 512] f32
// max_:   [32, 192, 1, 1]   f32
// min_:   [32, 192, 1, 1]   f32
// ycbcr_w:[3, 3]            f32
// dct_w:  [192, 1, 8, 8]    f32 (separable basis hardcoded below)
// out:    [32, 192, 64, 64] f32

#define HW 512
#define CHST (HW * HW)       // channel stride in x
#define NPAIR 6144           // 32 * 192 (b, out-channel) pairs
#define EPS 1e-6f

// basis[u][i] = c(u) * cos(pi*u*(i+0.5)/8); c(0)=sqrt(1/8), c(u>0)=0.5
static constexpr float BASIS[8][8] = {
  { 0.35355339059327373f, 0.35355339059327373f, 0.35355339059327373f, 0.35355339059327373f,
    0.35355339059327373f, 0.35355339059327373f, 0.35355339059327373f, 0.35355339059327373f },
  { 0.49039264020161522f, 0.41573480615127262f, 0.27778511650980114f, 0.09754516100806412f,
   -0.09754516100806412f,-0.27778511650980114f,-0.41573480615127262f,-0.49039264020161522f },
  { 0.46193976625564337f, 0.19134171618254492f,-0.19134171618254492f,-0.46193976625564337f,
   -0.46193976625564337f,-0.19134171618254492f, 0.19134171618254492f, 0.46193976625564337f },
  { 0.41573480615127262f,-0.09754516100806412f,-0.49039264020161522f,-0.27778511650980114f,
    0.27778511650980114f, 0.49039264020161522f, 0.09754516100806412f,-0.41573480615127262f },
  { 0.35355339059327373f,-0.35355339059327373f,-0.35355339059327373f, 0.35355339059327373f,
    0.35355339059327373f,-0.35355339059327373f,-0.35355339059327373f, 0.35355339059327373f },
  { 0.27778511650980114f,-0.49039264020161522f, 0.09754516100806412f, 0.41573480615127262f,
   -0.41573480615127262f,-0.09754516100806412f, 0.49039264020161522f,-0.27778511650980114f },
  { 0.19134171618254492f,-0.46193976625564337f, 0.46193976625564337f,-0.19134171618254492f,
   -0.19134171618254492f, 0.46193976625564337f,-0.46193976625564337f, 0.19134171618254492f },
  { 0.09754516100806412f,-0.27778511650980114f, 0.41573480615127262f,-0.49039264020161522f,
    0.49039264020161522f,-0.41573480615127262f, 0.27778511650980114f,-0.09754516100806412f }
};

// t_32 = a^32 * t0 - min * sum_{k=1..32} a^k, a = 1/(max-min+eps)
__global__ void precomp_norm(const float* __restrict__ max_,
                             const float* __restrict__ min_,
                             float* __restrict__ so) {
    int i = blockIdx.x * 256 + threadIdx.x;
    if (i >= NPAIR) return;
    float mn = min_[i], mx = max_[i];
    float d = mx - mn + EPS;
    float a = 1.0f / d;
    float a2 = a * a, a4 = a2 * a2, a8 = a4 * a4, a16 = a8 * a8, a32 = a16 * a16;
    float geo = a * (1.0f - a32) / (1.0f - a);   // sum_{k=1..32} a^k
    so[2 * i]     = a32;
    so[2 * i + 1] = -mn * geo;
}

template <bool USE_WS>
__global__ __launch_bounds__(192)
void dct_kernel(const float* __restrict__ x,
                const float* __restrict__ ycbcr_w,
                const float* __restrict__ so,
                const float* __restrict__ max_,
                const float* __restrict__ min_,
                float* __restrict__ out) {
    const int b  = blockIdx.x >> 6;        // batch
    const int by = blockIdx.x & 63;        // block-row
    const int c  = threadIdx.x >> 6;       // wave id = YCbCr channel (0..2)
    const int bx = threadIdx.x & 63;       // lane = block-col -> coalesced stores

    // wave-uniform YCbCr weights (row c)
    const float w0 = ycbcr_w[c * 3 + 0];
    const float w1 = ycbcr_w[c * 3 + 1];
    const float w2 = ycbcr_w[c * 3 + 2];

    const float* x0 = x + (size_t)(b * 3) * CHST + (by * 8) * HW + bx * 8;

    float tmp[8][8];     // row-pass result: tmp[u][j] = sum_i basis[u][i]*y[i][j]
#pragma unroll
    for (int u = 0; u < 8; ++u)
#pragma unroll
        for (int j = 0; j < 8; ++j) tmp[u][j] = 0.0f;

#pragma unroll
    for (int i = 0; i < 8; ++i) {
        const float* r = x0 + i * HW;
        float R[8], G[8], Bl[8];
        *(float4*)(&R[0])  = *(const float4*)(r);
        *(float4*)(&R[4])  = *(const float4*)(r + 4);
        *(float4*)(&G[0])  = *(const float4*)(r + CHST);
        *(float4*)(&G[4])  = *(const float4*)(r + CHST + 4);
        *(float4*)(&Bl[0]) = *(const float4*)(r + 2 * CHST);
        *(float4*)(&Bl[4]) = *(const float4*)(r + 2 * CHST + 4);
        float y[8];
#pragma unroll
        for (int j = 0; j < 8; ++j)
            y[j] = fmaf(w0, R[j], fmaf(w1, G[j], w2 * Bl[j]));
#pragma unroll
        for (int u = 0; u < 8; ++u) {
            const float bu = BASIS[u][i];
#pragma unroll
            for (int j = 0; j < 8; ++j)
                tmp[u][j] = fmaf(bu, y[j], tmp[u][j]);
        }
    }

    const int obase = b * 192 + c * 64;    // first output channel index (b,o)
    float* op = out + ((size_t)obase * 64 + by) * 64 + bx;

#pragma unroll
    for (int u = 0; u < 8; ++u) {
#pragma unroll
        for (int v = 0; v < 8; ++v) {
            float acc = tmp[u][0] * BASIS[v][0];
#pragma unroll
            for (int j = 1; j < 8; ++j)
                acc = fmaf(tmp[u][j], BASIS[v][j], acc);
            const int k = u * 8 + v;
            float s, o;
            if (USE_WS) {
                s = so[(obase + k) * 2];       // wave-uniform -> s_load
                o = so[(obase + k) * 2 + 1];
            } else {
                float mn = min_[obase + k], mx = max_[obase + k];
                float d  = mx - mn + EPS;
                float a  = 1.0f / d;
                float a2 = a * a, a4 = a2 * a2, a8 = a4 * a4, a16 = a8 * a8, a32 = a16 * a16;
                s = a32;
                o = -mn * (a * (1.0f - a32) / (1.0f - a));
            }
            op[(size_t)k * 4096] = fmaf(s, acc, o);   // lanes consecutive in bx
        }
    }
}

extern "C" void kernel_launch(void* const* d_in, const int* in_sizes, int n_in,
                              void* d_out, int out_size, void* d_ws, size_t ws_size,
                              hipStream_t stream) {
    const float* x    = (const float*)d_in[0];
    const float* max_ = (const float*)d_in[1];
    const float* min_ = (const float*)d_in[2];
    const float* yw   = (const float*)d_in[3];
    float* out = (float*)d_out;
    float* so  = (float*)d_ws;

    const bool use_ws = (ws_size >= (size_t)NPAIR * 2 * sizeof(float));
    if (use_ws) {
        precomp_norm<<<(NPAIR + 255) / 256, 256, 0, stream>>>(max_, min_, so);
        dct_kernel<true><<<32 * 64, 192, 0, stream>>>(x, yw, so, max_, min_, out);
    } else {
        dct_kernel<false><<<32 * 64, 192, 0, stream>>>(x, yw, nullptr, max_, min_, out);
    }
}

// Round 2
// 187.350 us; speedup vs baseline: 1.0548x; 1.0548x over previous
//
#include <hip/hip_runtime.h>

// DCT_18769007084406: RGB->YCbCr (1x1 conv) -> 8x8 stride-8 block DCT
// (grouped conv) -> 32x repeated (t-min)/d normalization (closed form).
//
// R2: LDS-staged version. One 256-thread block per (b, block-row) band.
// Stage 1: 12 dense independent float4 loads/thread (max MLP, fully
// coalesced), RGB->YCbCr in registers, Y staged to 48 KB LDS.
// Stage 2: 192 threads (3 waves = 3 channels, lane = block-col) do the
// separable 8x8 DCT from LDS in registers, fused closed-form norm, stores
// coalesced 256B per wave per k.

#define HW 512
#define CHST (HW * HW)       // channel stride in x
#define NPAIR 6144           // 32 * 192 (b, out-channel) pairs
#define EPS 1e-6f

// basis[u][i] = c(u) * cos(pi*u*(i+0.5)/8); c(0)=sqrt(1/8), c(u>0)=0.5
static constexpr float BASIS[8][8] = {
  { 0.35355339059327373f, 0.35355339059327373f, 0.35355339059327373f, 0.35355339059327373f,
    0.35355339059327373f, 0.35355339059327373f, 0.35355339059327373f, 0.35355339059327373f },
  { 0.49039264020161522f, 0.41573480615127262f, 0.27778511650980114f, 0.09754516100806412f,
   -0.09754516100806412f,-0.27778511650980114f,-0.41573480615127262f,-0.49039264020161522f },
  { 0.46193976625564337f, 0.19134171618254492f,-0.19134171618254492f,-0.46193976625564337f,
   -0.46193976625564337f,-0.19134171618254492f, 0.19134171618254492f, 0.46193976625564337f },
  { 0.41573480615127262f,-0.09754516100806412f,-0.49039264020161522f,-0.27778511650980114f,
    0.27778511650980114f, 0.49039264020161522f, 0.09754516100806412f,-0.41573480615127262f },
  { 0.35355339059327373f,-0.35355339059327373f,-0.35355339059327373f, 0.35355339059327373f,
    0.35355339059327373f,-0.35355339059327373f,-0.35355339059327373f, 0.35355339059327373f },
  { 0.27778511650980114f,-0.49039264020161522f, 0.09754516100806412f, 0.41573480615127262f,
   -0.41573480615127262f,-0.09754516100806412f, 0.49039264020161522f,-0.27778511650980114f },
  { 0.19134171618254492f,-0.46193976625564337f, 0.46193976625564337f,-0.19134171618254492f,
   -0.19134171618254492f, 0.46193976625564337f,-0.46193976625564337f, 0.19134171618254492f },
  { 0.09754516100806412f,-0.27778511650980114f, 0.41573480615127262f,-0.49039264020161522f,
    0.49039264020161522f,-0.41573480615127262f, 0.27778511650980114f,-0.09754516100806412f }
};

// t_32 = a^32 * t0 - min * sum_{k=1..32} a^k, a = 1/(max-min+eps)
__global__ void precomp_norm(const float* __restrict__ max_,
                             const float* __restrict__ min_,
                             float* __restrict__ so) {
    int i = blockIdx.x * 256 + threadIdx.x;
    if (i >= NPAIR) return;
    float mn = min_[i], mx = max_[i];
    float d = mx - mn + EPS;
    float a = 1.0f / d;
    float a2 = a * a, a4 = a2 * a2, a8 = a4 * a4, a16 = a8 * a8, a32 = a16 * a16;
    float geo = a * (1.0f - a32) / (1.0f - a);   // sum_{k=1..32} a^k
    so[2 * i]     = a32;
    so[2 * i + 1] = -mn * geo;
}

template <bool USE_WS>
__global__ __launch_bounds__(256)
void dct_kernel(const float* __restrict__ x,
                const float* __restrict__ ycbcr_w,
                const float* __restrict__ so,
                const float* __restrict__ max_,
                const float* __restrict__ min_,
                float* __restrict__ out) {
    // Y/Cb/Cr band: [3][8 rows][512 cols] floats = 48 KB
    __shared__ float ylds[3 * 8 * HW];

    const int b  = blockIdx.x >> 6;        // batch
    const int by = blockIdx.x & 63;        // block-row
    const int t  = threadIdx.x;

    // ---------- stage 1: band load (dense, all loads independent) ----------
    const float* band = x + (size_t)(b * 3) * CHST + (by * 8) * HW;

    float w00 = ycbcr_w[0], w01 = ycbcr_w[1], w02 = ycbcr_w[2];
    float w10 = ycbcr_w[3], w11 = ycbcr_w[4], w12 = ycbcr_w[5];
    float w20 = ycbcr_w[6], w21 = ycbcr_w[7], w22 = ycbcr_w[8];

    // 1024 float4s per 16 KB channel chunk; 256 threads x 4 each.
    float4 Rv[4], Gv[4], Bv[4];
#pragma unroll
    for (int w = 0; w < 4; ++w) {
        const int o = t + 256 * w;
        Rv[w] = ((const float4*)(band))[o];
        Gv[w] = ((const float4*)(band + CHST))[o];
        Bv[w] = ((const float4*)(band + 2 * CHST))[o];
    }
    float4* yv = (float4*)ylds;
#pragma unroll
    for (int w = 0; w < 4; ++w) {
        const int o = t + 256 * w;
        float4 y0, y1, y2;
        y0.x = fmaf(w00, Rv[w].x, fmaf(w01, Gv[w].x, w02 * Bv[w].x));
        y0.y = fmaf(w00, Rv[w].y, fmaf(w01, Gv[w].y, w02 * Bv[w].y));
        y0.z = fmaf(w00, Rv[w].z, fmaf(w01, Gv[w].z, w02 * Bv[w].z));
        y0.w = fmaf(w00, Rv[w].w, fmaf(w01, Gv[w].w, w02 * Bv[w].w));
        y1.x = fmaf(w10, Rv[w].x, fmaf(w11, Gv[w].x, w12 * Bv[w].x));
        y1.y = fmaf(w10, Rv[w].y, fmaf(w11, Gv[w].y, w12 * Bv[w].y));
        y1.z = fmaf(w10, Rv[w].z, fmaf(w11, Gv[w].z, w12 * Bv[w].z));
        y1.w = fmaf(w10, Rv[w].w, fmaf(w11, Gv[w].w, w12 * Bv[w].w));
        y2.x = fmaf(w20, Rv[w].x, fmaf(w21, Gv[w].x, w22 * Bv[w].x));
        y2.y = fmaf(w20, Rv[w].y, fmaf(w21, Gv[w].y, w22 * Bv[w].y));
        y2.z = fmaf(w20, Rv[w].z, fmaf(w21, Gv[w].z, w22 * Bv[w].z));
        y2.w = fmaf(w20, Rv[w].w, fmaf(w21, Gv[w].w, w22 * Bv[w].w));
        yv[o]          = y0;
        yv[1024 + o]   = y1;
        yv[2048 + o]   = y2;
    }
    __syncthreads();

    // ---------- stage 2: separable DCT per 8x8 block ----------
    if (t < 192) {
        const int c  = t >> 6;             // wave = YCbCr channel
        const int bx = t & 63;             // lane = block-col -> coalesced stores

        const float* yl = ylds + c * (8 * HW) + bx * 8;

        float tmp[8][8];   // tmp[u][j] = sum_i basis[u][i] * y[i][j]
#pragma unroll
        for (int u = 0; u < 8; ++u)
#pragma unroll
            for (int j = 0; j < 8; ++j) tmp[u][j] = 0.0f;

#pragma unroll
        for (int i = 0; i < 8; ++i) {
            float y[8];
            *(float4*)(&y[0]) = *(const float4*)(yl + i * HW);
            *(float4*)(&y[4]) = *(const float4*)(yl + i * HW + 4);
#pragma unroll
            for (int u = 0; u < 8; ++u) {
                const float bu = BASIS[u][i];
#pragma unroll
                for (int j = 0; j < 8; ++j)
                    tmp[u][j] = fmaf(bu, y[j], tmp[u][j]);
            }
        }

        const int obase = b * 192 + c * 64;  // first output channel index
        float* op = out + ((size_t)obase * 64 + by) * 64 + bx;

#pragma unroll
        for (int u = 0; u < 8; ++u) {
#pragma unroll
            for (int v = 0; v < 8; ++v) {
                float acc = tmp[u][0] * BASIS[v][0];
#pragma unroll
                for (int j = 1; j < 8; ++j)
                    acc = fmaf(tmp[u][j], BASIS[v][j], acc);
                const int k = u * 8 + v;
                float s, o;
                if (USE_WS) {
                    s = so[(obase + k) * 2];       // wave-uniform
                    o = so[(obase + k) * 2 + 1];
                } else {
                    float mn = min_[obase + k], mx = max_[obase + k];
                    float d  = mx - mn + EPS;
                    float a  = 1.0f / d;
                    float a2 = a * a, a4 = a2 * a2, a8 = a4 * a4, a16 = a8 * a8, a32 = a16 * a16;
                    s = a32;
                    o = -mn * (a * (1.0f - a32) / (1.0f - a));
                }
                op[(size_t)k * 4096] = fmaf(s, acc, o);  // lanes consecutive in bx
            }
        }
    }
}

extern "C" void kernel_launch(void* const* d_in, const int* in_sizes, int n_in,
                              void* d_out, int out_size, void* d_ws, size_t ws_size,
                              hipStream_t stream) {
    const float* x    = (const float*)d_in[0];
    const float* max_ = (const float*)d_in[1];
    const float* min_ = (const float*)d_in[2];
    const float* yw   = (const float*)d_in[3];
    float* out = (float*)d_out;
    float* so  = (float*)d_ws;

    const bool use_ws = (ws_size >= (size_t)NPAIR * 2 * sizeof(float));
    if (use_ws) {
        precomp_norm<<<(NPAIR + 255) / 256, 256, 0, stream>>>(max_, min_, so);
        dct_kernel<true><<<32 * 64, 256, 0, stream>>>(x, yw, so, max_, min_, out);
    } else {
        dct_kernel<false><<<32 * 64, 256, 0, stream>>>(x, yw, nullptr, max_, min_, out);
    }
}